// Round 2
// baseline (949.990 us; speedup 1.0000x reference)
//
#include <hip/hip_runtime.h>

#define N_NODES 50000
#define C_DIM   128
#define E_EDGES 1600000
#define NUM_IDX 2048

// K1: multiplicity histogram of `id` -> cnt[N]
__global__ void hist_id_kernel(const int* __restrict__ id, int* __restrict__ cnt) {
    int i = blockIdx.x * blockDim.x + threadIdx.x;
    if (i < NUM_IDX) atomicAdd(&cnt[id[i]], 1);
}

// K2: out-degree histogram over row[] -> deg[N] (self loop accounted as +1 later)
__global__ void hist_deg_kernel(const int* __restrict__ row, int* __restrict__ deg) {
    int i = blockIdx.x * blockDim.x + threadIdx.x;
    if (i < E_EDGES) atomicAdd(&deg[row[i]], 1);
}

// K3 (fused): per node n (one 128-thread block, thread t = channel t):
//   x1 = x[n] + cnt[n] * (x[n] @ W)
//   ox = x1 + (L>0 ? x1 @ W_id[L-1] : 0)
//   msg[n] = dinv[n] * ox   where dinv = (outdeg+1)^-1/2
__global__ void node_msg_kernel(const float* __restrict__ x,
                                const int* __restrict__ cnt,
                                const int* __restrict__ label,
                                const int* __restrict__ deg,
                                const float* __restrict__ W,
                                const float* __restrict__ Wid,
                                float* __restrict__ msg) {
    int n = blockIdx.x;
    int t = threadIdx.x;
    __shared__ float xs[C_DIM];
    __shared__ float ys[C_DIM];
    float v = x[(size_t)n * C_DIM + t];
    xs[t] = v;
    __syncthreads();
    int c = cnt[n];                        // block-uniform
    if (c > 0) {
        float acc = 0.f;
        #pragma unroll 16
        for (int k = 0; k < C_DIM; ++k)
            acc += xs[k] * W[(size_t)k * C_DIM + t];
        v += (float)c * acc;
    }
    ys[t] = v;
    __syncthreads();
    int L = label[n];                      // block-uniform, 0..7
    if (L > 0) {
        const float* Wl = Wid + (size_t)(L - 1) * C_DIM * C_DIM;
        float acc = 0.f;
        #pragma unroll 16
        for (int k = 0; k < C_DIM; ++k)
            acc += ys[k] * Wl[(size_t)k * C_DIM + t];
        v += acc;
    }
    float di = rsqrtf((float)(deg[n] + 1));
    msg[(size_t)n * C_DIM + t] = di * v;
}

// K4: edge scatter. acc[col] += msg[row]. 2 edges per 256-thread block.
__global__ void scatter_kernel(const int* __restrict__ row,
                               const int* __restrict__ col,
                               const float* __restrict__ msg,
                               float* __restrict__ acc) {
    int e  = blockIdx.x * 2 + (threadIdx.x >> 7);
    int ch = threadIdx.x & (C_DIM - 1);
    if (e < E_EDGES) {
        int r = row[e];
        int c = col[e];
        float v = msg[(size_t)r * C_DIM + ch];
        atomicAdd(&acc[(size_t)c * C_DIM + ch], v);
    }
}

// K5: out[n] = dinv[n] * (acc_out[n] + msg[n])   (in place on d_out)
__global__ void finalize_kernel(const int* __restrict__ deg,
                                const float* __restrict__ msg,
                                float* __restrict__ out) {
    int n = blockIdx.x;
    int t = threadIdx.x;
    float di = rsqrtf((float)(deg[n] + 1));
    size_t idx = (size_t)n * C_DIM + t;
    out[idx] = di * (out[idx] + msg[idx]);
}

extern "C" void kernel_launch(void* const* d_in, const int* in_sizes, int n_in,
                              void* d_out, int out_size, void* d_ws, size_t ws_size,
                              hipStream_t stream) {
    const float* x     = (const float*)d_in[0];
    const int*   edge  = (const int*)d_in[1];   // [2][E]
    const int*   id    = (const int*)d_in[2];
    const int*   label = (const int*)d_in[3];
    const float* W     = (const float*)d_in[4];
    const float* Wid   = (const float*)d_in[5];
    float*       out   = (float*)d_out;

    const int* row = edge;
    const int* col = edge + E_EDGES;

    // workspace: cnt[N] int | deg[N] int | msg[N*C] f32   (~26 MB)
    int*   cnt = (int*)d_ws;
    int*   deg = cnt + N_NODES;
    float* msg = (float*)(deg + N_NODES);

    hipMemsetAsync(cnt, 0, 2 * (size_t)N_NODES * sizeof(int), stream);
    hipMemsetAsync(out, 0, (size_t)N_NODES * C_DIM * sizeof(float), stream);

    hist_id_kernel <<<(NUM_IDX + 255) / 256, 256, 0, stream>>>(id, cnt);
    hist_deg_kernel<<<(E_EDGES + 255) / 256, 256, 0, stream>>>(row, deg);
    node_msg_kernel<<<N_NODES, C_DIM, 0, stream>>>(x, cnt, label, deg, W, Wid, msg);
    scatter_kernel <<<E_EDGES / 2, 256, 0, stream>>>(row, col, msg, out);
    finalize_kernel<<<N_NODES, C_DIM, 0, stream>>>(deg, msg, out);
}

// Round 3
// 659.123 us; speedup vs baseline: 1.4413x; 1.4413x over previous
//
#include <hip/hip_runtime.h>

#define N_NODES 50000
#define C_DIM   128
#define E_EDGES 1600000
#define NUM_IDX 2048
#define SCAN_T  1024

// K1: multiplicity histogram of `id` -> cnt[N]
__global__ void hist_id_kernel(const int* __restrict__ id, int* __restrict__ cnt) {
    int i = blockIdx.x * blockDim.x + threadIdx.x;
    if (i < NUM_IDX) atomicAdd(&cnt[id[i]], 1);
}

// K2: out-degree (row) histogram -> deg[N]; in-degree (col) histogram -> colh[N]
__global__ void hist_edges_kernel(const int* __restrict__ row, const int* __restrict__ col,
                                  int* __restrict__ deg, int* __restrict__ colh) {
    int i = blockIdx.x * blockDim.x + threadIdx.x;
    if (i < E_EDGES) {
        atomicAdd(&deg[row[i]], 1);
        atomicAdd(&colh[col[i]], 1);
    }
}

// K3: exclusive scan of colh -> start[N+1]; also init cursor[c] = start[c].
// Single block of 1024 threads, each owning a contiguous chunk.
__global__ void scan_kernel(const int* __restrict__ colh,
                            int* __restrict__ start, int* __restrict__ cursor) {
    __shared__ int part[SCAN_T];
    const int CH = (N_NODES + SCAN_T - 1) / SCAN_T;   // 49
    int tid = threadIdx.x;
    int base = tid * CH;
    int s = 0;
    for (int i = 0; i < CH; ++i) {
        int idx = base + i;
        if (idx < N_NODES) s += colh[idx];
    }
    part[tid] = s;
    __syncthreads();
    for (int off = 1; off < SCAN_T; off <<= 1) {
        int v = part[tid];
        int add = (tid >= off) ? part[tid - off] : 0;
        __syncthreads();
        part[tid] = v + add;
        __syncthreads();
    }
    int run = (tid == 0) ? 0 : part[tid - 1];          // exclusive prefix
    for (int i = 0; i < CH; ++i) {
        int idx = base + i;
        if (idx < N_NODES) {
            start[idx] = run;
            cursor[idx] = run;
            run += colh[idx];
        }
    }
    if (tid == SCAN_T - 1) start[N_NODES] = run;       // == E_EDGES
}

// K4: bucket-fill CSR: for each edge, place its source row into the dest bucket.
__global__ void build_csr_kernel(const int* __restrict__ row, const int* __restrict__ col,
                                 int* __restrict__ cursor, int* __restrict__ srcrow) {
    int i = blockIdx.x * blockDim.x + threadIdx.x;
    if (i < E_EDGES) {
        int p = atomicAdd(&cursor[col[i]], 1);
        srcrow[p] = row[i];
    }
}

// K5 (fused node transform): per node n (128-thread block, thread t = channel t):
//   x1 = x[n] + cnt[n] * (x[n] @ W)
//   ox = x1 + (L>0 ? x1 @ W_id[L-1] : 0)
//   msg[n] = dinv[n] * ox,  dinv = (outdeg+1)^-1/2
__global__ void node_msg_kernel(const float* __restrict__ x,
                                const int* __restrict__ cnt,
                                const int* __restrict__ label,
                                const int* __restrict__ deg,
                                const float* __restrict__ W,
                                const float* __restrict__ Wid,
                                float* __restrict__ msg) {
    int n = blockIdx.x;
    int t = threadIdx.x;
    __shared__ float xs[C_DIM];
    __shared__ float ys[C_DIM];
    float v = x[(size_t)n * C_DIM + t];
    xs[t] = v;
    __syncthreads();
    int c = cnt[n];                        // block-uniform
    if (c > 0) {
        float acc = 0.f;
        #pragma unroll 16
        for (int k = 0; k < C_DIM; ++k)
            acc += xs[k] * W[(size_t)k * C_DIM + t];
        v += (float)c * acc;
    }
    ys[t] = v;
    __syncthreads();
    int L = label[n];                      // block-uniform, 0..7
    if (L > 0) {
        const float* Wl = Wid + (size_t)(L - 1) * C_DIM * C_DIM;
        float acc = 0.f;
        #pragma unroll 16
        for (int k = 0; k < C_DIM; ++k)
            acc += ys[k] * Wl[(size_t)k * C_DIM + t];
        v += acc;
    }
    float di = rsqrtf((float)(deg[n] + 1));
    msg[(size_t)n * C_DIM + t] = di * v;
}

// K6: gather + finalize. out[c] = dinv[c] * (msg[c] + sum_{e in CSR[c]} msg[src[e]])
__global__ void gather_kernel(const int* __restrict__ start,
                              const int* __restrict__ srcrow,
                              const int* __restrict__ deg,
                              const float* __restrict__ msg,
                              float* __restrict__ out) {
    int c = blockIdx.x;
    int t = threadIdx.x;
    int e0 = start[c], e1 = start[c + 1];
    float acc = msg[(size_t)c * C_DIM + t];            // self-loop message
    int e = e0;
    for (; e + 4 <= e1; e += 4) {                      // 4-deep MLP
        int r0 = srcrow[e], r1 = srcrow[e + 1], r2 = srcrow[e + 2], r3 = srcrow[e + 3];
        float v0 = msg[(size_t)r0 * C_DIM + t];
        float v1 = msg[(size_t)r1 * C_DIM + t];
        float v2 = msg[(size_t)r2 * C_DIM + t];
        float v3 = msg[(size_t)r3 * C_DIM + t];
        acc += (v0 + v1) + (v2 + v3);
    }
    for (; e < e1; ++e)
        acc += msg[(size_t)srcrow[e] * C_DIM + t];
    float di = rsqrtf((float)(deg[c] + 1));
    out[(size_t)c * C_DIM + t] = di * acc;
}

extern "C" void kernel_launch(void* const* d_in, const int* in_sizes, int n_in,
                              void* d_out, int out_size, void* d_ws, size_t ws_size,
                              hipStream_t stream) {
    const float* x     = (const float*)d_in[0];
    const int*   edge  = (const int*)d_in[1];   // [2][E]
    const int*   id    = (const int*)d_in[2];
    const int*   label = (const int*)d_in[3];
    const float* W     = (const float*)d_in[4];
    const float* Wid   = (const float*)d_in[5];
    float*       out   = (float*)d_out;

    const int* row = edge;
    const int* col = edge + E_EDGES;

    // ws layout: msg[N*C] f32 | cnt[N] | deg[N] | colh[N] | start[N+1] | cursor[N] | srcrow[E]
    float* msg    = (float*)d_ws;
    int*   cnt    = (int*)(msg + (size_t)N_NODES * C_DIM);
    int*   deg    = cnt + N_NODES;
    int*   colh   = deg + N_NODES;
    int*   start  = colh + N_NODES;
    int*   cursor = start + (N_NODES + 1);
    int*   srcrow = cursor + N_NODES;

    // zero cnt|deg|colh (contiguous)
    hipMemsetAsync(cnt, 0, 3 * (size_t)N_NODES * sizeof(int), stream);

    hist_id_kernel   <<<(NUM_IDX + 255) / 256, 256, 0, stream>>>(id, cnt);
    hist_edges_kernel<<<(E_EDGES + 255) / 256, 256, 0, stream>>>(row, col, deg, colh);
    scan_kernel      <<<1, SCAN_T, 0, stream>>>(colh, start, cursor);
    build_csr_kernel <<<(E_EDGES + 255) / 256, 256, 0, stream>>>(row, col, cursor, srcrow);
    node_msg_kernel  <<<N_NODES, C_DIM, 0, stream>>>(x, cnt, label, deg, W, Wid, msg);
    gather_kernel    <<<N_NODES, C_DIM, 0, stream>>>(start, srcrow, deg, msg, out);
}

// Round 4
// 359.706 us; speedup vs baseline: 2.6410x; 1.8324x over previous
//
#include <hip/hip_runtime.h>

#define N_NODES 50000
#define C_DIM   128
#define E_EDGES 1600000
#define NUM_IDX 2048

#define CPB 256                    // cols per coarse bucket (col >> 8)
#define NB  196                    // ceil(N/CPB)
#define CHK 8192                   // edges per chunk
#define NP  196                    // ceil(E/CHK)
#define GB  8                      // nodes per label-matmul block

// K1: multiplicity histogram of `id` -> cnt[N]
__global__ void hist_id_kernel(const int* __restrict__ id, int* __restrict__ cnt) {
    int i = blockIdx.x * blockDim.x + threadIdx.x;
    if (i < NUM_IDX) atomicAdd(&cnt[id[i]], 1);
}

// K2: per-chunk coarse histogram of col buckets -> H[p][b]
__global__ void coarse_hist_kernel(const int* __restrict__ col, int* __restrict__ H) {
    __shared__ int h[NB];
    int p = blockIdx.x;
    for (int i = threadIdx.x; i < NB; i += 256) h[i] = 0;
    __syncthreads();
    int e0 = p * CHK, e1 = min(e0 + CHK, E_EDGES);
    for (int e = e0 + threadIdx.x; e < e1; e += 256)
        atomicAdd(&h[col[e] >> 8], 1);
    __syncthreads();
    for (int i = threadIdx.x; i < NB; i += 256) H[p * NB + i] = h[i];
}

// K3: turn H into per-(chunk,bucket) write offsets (in place); bucketStart[NB+1].
// Single block, thread b owns bucket b.
__global__ void offsets_kernel(int* __restrict__ H, int* __restrict__ bucketStart) {
    __shared__ int tot[256];
    int b = threadIdx.x;
    int t = 0;
    if (b < NB) for (int p = 0; p < NP; ++p) t += H[p * NB + b];
    tot[b] = t;
    __syncthreads();
    for (int off = 1; off < 256; off <<= 1) {
        int v = tot[b];
        int a = (b >= off) ? tot[b - off] : 0;
        __syncthreads();
        tot[b] = v + a;
        __syncthreads();
    }
    int base = (b == 0) ? 0 : tot[b - 1];          // exclusive prefix
    if (b < NB) {
        bucketStart[b] = base;
        if (b == NB - 1) bucketStart[NB] = base + t;   // == E
        int run = base;
        for (int p = 0; p < NP; ++p) {
            int hv = H[p * NB + b];
            H[p * NB + b] = run;
            run += hv;
        }
    }
}

// K4: partition edges into bucket-contiguous staging S[(row,col)]; fold deg histogram.
__global__ void partition_kernel(const int* __restrict__ row, const int* __restrict__ col,
                                 const int* __restrict__ H, int2* __restrict__ S,
                                 int* __restrict__ deg) {
    __shared__ int cur[NB];
    int p = blockIdx.x;
    for (int i = threadIdx.x; i < NB; i += 256) cur[i] = H[p * NB + i];
    __syncthreads();
    int e0 = p * CHK, e1 = min(e0 + CHK, E_EDGES);
    for (int e = e0 + threadIdx.x; e < e1; e += 256) {
        int r = row[e], c = col[e];
        atomicAdd(&deg[r], 1);
        int pos = atomicAdd(&cur[c >> 8], 1);
        S[pos] = make_int2(r, c);
    }
}

// K5: per-bucket fine CSR: col counts -> LDS scan -> start[] + srcrow placement.
__global__ void fine_csr_kernel(const int2* __restrict__ S,
                                const int* __restrict__ bucketStart,
                                int* __restrict__ start, int* __restrict__ srcrow) {
    __shared__ int h[CPB], cur[CPB], sc[CPB];
    int b = blockIdx.x, t = threadIdx.x;
    h[t] = 0;
    __syncthreads();
    int e0 = bucketStart[b], e1 = bucketStart[b + 1];
    for (int e = e0 + t; e < e1; e += 256) atomicAdd(&h[S[e].y & 255], 1);
    __syncthreads();
    sc[t] = h[t];
    __syncthreads();
    for (int off = 1; off < 256; off <<= 1) {
        int v = sc[t];
        int a = (t >= off) ? sc[t - off] : 0;
        __syncthreads();
        sc[t] = v + a;
        __syncthreads();
    }
    int base = (t == 0) ? 0 : sc[t - 1];               // exclusive within bucket
    int gcol = b * CPB + t;
    if (gcol < N_NODES) start[gcol] = e0 + base;
    if (b == NB - 1 && t == 0) start[N_NODES] = E_EDGES;
    cur[t] = base;
    __syncthreads();
    for (int e = e0 + t; e < e1; e += 256) {
        int2 rc = S[e];
        int pos = atomicAdd(&cur[rc.y & 255], 1);
        srcrow[e0 + pos] = rc.x;
    }
}

// K6a: label histogram (LDS-staged)
__global__ void label_hist_kernel(const int* __restrict__ label, int* __restrict__ labCnt) {
    __shared__ int h[8];
    if (threadIdx.x < 8) h[threadIdx.x] = 0;
    __syncthreads();
    int n = blockIdx.x * 256 + threadIdx.x;
    if (n < N_NODES) atomicAdd(&h[label[n]], 1);
    __syncthreads();
    if (threadIdx.x < 8 && h[threadIdx.x] > 0) atomicAdd(&labCnt[threadIdx.x], h[threadIdx.x]);
}

// K6b: label bases -> labCur
__global__ void label_base_kernel(const int* __restrict__ labCnt, int* __restrict__ labCur) {
    if (threadIdx.x == 0) {
        int run = 0;
        for (int i = 0; i < 8; ++i) { labCur[i] = run; run += labCnt[i]; }
    }
}

// K6c: compact nodes grouped by label (block-ranked, 8 global atomics per block)
__global__ void label_fill_kernel(const int* __restrict__ label, int* __restrict__ labCur,
                                  int* __restrict__ nodeByLabel) {
    __shared__ int h[8], base[8], c2[8];
    int t = threadIdx.x;
    if (t < 8) { h[t] = 0; c2[t] = 0; }
    __syncthreads();
    int n = blockIdx.x * 256 + t;
    int l = 0;
    if (n < N_NODES) { l = label[n]; atomicAdd(&h[l], 1); }
    __syncthreads();
    if (t < 8 && h[t] > 0) base[t] = atomicAdd(&labCur[t], h[t]);
    __syncthreads();
    if (n < N_NODES) {
        int pos = base[l] + atomicAdd(&c2[l], 1);
        nodeByLabel[pos] = n;
    }
}

// K7: label-grouped node transform. Block = 128 threads (thread t = channel t),
// GB=8 same-label nodes per block (label-uniform except <=7 straddle blocks).
//   x1 = x + cnt*(x@W); ox = x1 + (L>0 ? x1@Wid[L-1] : 0); msg = dinv*ox
__global__ void node_msg_kernel(const float* __restrict__ x,
                                const int* __restrict__ cnt,
                                const int* __restrict__ label,
                                const int* __restrict__ deg,
                                const float* __restrict__ W,
                                const float* __restrict__ Wid,
                                const int* __restrict__ nodeByLabel,
                                float* __restrict__ msg) {
    __shared__ float xs[GB][C_DIM];
    __shared__ int nid[GB], lab[GB], cc[GB];
    int t = threadIdx.x;
    if (t < GB) {
        int n = nodeByLabel[blockIdx.x * GB + t];
        nid[t] = n; lab[t] = label[n]; cc[t] = cnt[n];
    }
    __syncthreads();
    #pragma unroll
    for (int g = 0; g < GB; ++g)
        xs[g][t] = x[(size_t)nid[g] * C_DIM + t];
    __syncthreads();
    // ego update (block-uniform branch; ~4% of nodes)
    for (int g = 0; g < GB; ++g) {
        int c = cc[g];
        if (c > 0) {
            float acc = 0.f;
            #pragma unroll 8
            for (int k = 0; k < C_DIM; ++k) acc += xs[g][k] * W[k * C_DIM + t];
            __syncthreads();
            xs[g][t] += (float)c * acc;
            __syncthreads();
        }
    }
    float res[GB];
    #pragma unroll
    for (int g = 0; g < GB; ++g) res[g] = xs[g][t];
    if (lab[0] == lab[GB - 1]) {
        // fast path: uniform label
        int L = lab[0];
        if (L > 0) {
            const float* Wl = Wid + (size_t)(L - 1) * C_DIM * C_DIM;
            float acc[GB];
            #pragma unroll
            for (int g = 0; g < GB; ++g) acc[g] = 0.f;
            for (int k = 0; k < C_DIM; ++k) {
                float w = Wl[k * C_DIM + t];
                #pragma unroll
                for (int g = 0; g < GB; ++g) acc[g] += xs[g][k] * w;
            }
            #pragma unroll
            for (int g = 0; g < GB; ++g) res[g] += acc[g];
        }
    } else {
        // straddle block (rare): per-node loop
        for (int g = 0; g < GB; ++g) {
            int L = lab[g];
            if (L > 0) {
                const float* Wl = Wid + (size_t)(L - 1) * C_DIM * C_DIM;
                float acc = 0.f;
                #pragma unroll 8
                for (int k = 0; k < C_DIM; ++k) acc += xs[g][k] * Wl[k * C_DIM + t];
                res[g] += acc;
            }
        }
    }
    #pragma unroll
    for (int g = 0; g < GB; ++g) {
        int n = nid[g];
        float di = rsqrtf((float)(deg[n] + 1));
        msg[(size_t)n * C_DIM + t] = di * res[g];
    }
}

// K8: gather + finalize. out[c] = dinv[c] * (msg[c] + sum_{e in CSR[c]} msg[src[e]])
__global__ void gather_kernel(const int* __restrict__ start,
                              const int* __restrict__ srcrow,
                              const int* __restrict__ deg,
                              const float* __restrict__ msg,
                              float* __restrict__ out) {
    int c = blockIdx.x;
    int t = threadIdx.x;
    int e0 = start[c], e1 = start[c + 1];
    float acc = msg[(size_t)c * C_DIM + t];            // self-loop message
    int e = e0;
    for (; e + 4 <= e1; e += 4) {
        int r0 = srcrow[e], r1 = srcrow[e + 1], r2 = srcrow[e + 2], r3 = srcrow[e + 3];
        float v0 = msg[(size_t)r0 * C_DIM + t];
        float v1 = msg[(size_t)r1 * C_DIM + t];
        float v2 = msg[(size_t)r2 * C_DIM + t];
        float v3 = msg[(size_t)r3 * C_DIM + t];
        acc += (v0 + v1) + (v2 + v3);
    }
    for (; e < e1; ++e)
        acc += msg[(size_t)srcrow[e] * C_DIM + t];
    float di = rsqrtf((float)(deg[c] + 1));
    out[(size_t)c * C_DIM + t] = di * acc;
}

extern "C" void kernel_launch(void* const* d_in, const int* in_sizes, int n_in,
                              void* d_out, int out_size, void* d_ws, size_t ws_size,
                              hipStream_t stream) {
    const float* x     = (const float*)d_in[0];
    const int*   edge  = (const int*)d_in[1];   // [2][E]
    const int*   id    = (const int*)d_in[2];
    const int*   label = (const int*)d_in[3];
    const float* W     = (const float*)d_in[4];
    const float* Wid   = (const float*)d_in[5];
    float*       out   = (float*)d_out;

    const int* row = edge;
    const int* col = edge + E_EDGES;

    // ws layout (8B-aligned first):
    // msg[N*C] f32 | S[NP*CHK] int2 | srcrow[E] | H[NP*NB] | bucketStart[NB+1] |
    // start[N+1] | cnt[N] | deg[N] | labCnt[8] | labCur[8] | nodeByLabel[N]
    float* msg         = (float*)d_ws;
    int2*  S           = (int2*)(msg + (size_t)N_NODES * C_DIM);
    int*   srcrow      = (int*)(S + (size_t)NP * CHK);
    int*   H           = srcrow + E_EDGES;
    int*   bucketStart = H + NP * NB;
    int*   start       = bucketStart + (NB + 1);
    int*   cnt         = start + (N_NODES + 1);
    int*   deg         = cnt + N_NODES;
    int*   labCnt      = deg + N_NODES;
    int*   labCur      = labCnt + 8;
    int*   nodeByLabel = labCur + 8;

    // zero cnt | deg | labCnt | labCur (contiguous)
    hipMemsetAsync(cnt, 0, (2 * (size_t)N_NODES + 16) * sizeof(int), stream);

    hist_id_kernel    <<<(NUM_IDX + 255) / 256, 256, 0, stream>>>(id, cnt);
    coarse_hist_kernel<<<NP, 256, 0, stream>>>(col, H);
    offsets_kernel    <<<1, 256, 0, stream>>>(H, bucketStart);
    partition_kernel  <<<NP, 256, 0, stream>>>(row, col, H, S, deg);
    fine_csr_kernel   <<<NB, 256, 0, stream>>>(S, bucketStart, start, srcrow);
    label_hist_kernel <<<(N_NODES + 255) / 256, 256, 0, stream>>>(label, labCnt);
    label_base_kernel <<<1, 64, 0, stream>>>(labCnt, labCur);
    label_fill_kernel <<<(N_NODES + 255) / 256, 256, 0, stream>>>(label, labCur, nodeByLabel);
    node_msg_kernel   <<<N_NODES / GB, C_DIM, 0, stream>>>(x, cnt, label, deg, W, Wid,
                                                           nodeByLabel, msg);
    gather_kernel     <<<N_NODES, C_DIM, 0, stream>>>(start, srcrow, deg, msg, out);
}

// Round 5
// 326.222 us; speedup vs baseline: 2.9121x; 1.1026x over previous
//
#include <hip/hip_runtime.h>
#include <hip/hip_bf16.h>

typedef unsigned int  u32;
typedef unsigned short u16;

#define N_NODES 50000
#define C_DIM   128
#define E_EDGES 1600000
#define NUM_IDX 2048

#define CPB 256                    // cols per coarse bucket (col >> 8)
#define NB  196                    // ceil(N/CPB)
#define CHK 8192                   // edges per chunk
#define NP  196                    // ceil(E/CHK)
#define GB  8                      // nodes per label-matmul block

// K1: multiplicity histogram of `id` -> cnt[N]
__global__ void hist_id_kernel(const int* __restrict__ id, int* __restrict__ cnt) {
    int i = blockIdx.x * blockDim.x + threadIdx.x;
    if (i < NUM_IDX) atomicAdd(&cnt[id[i]], 1);
}

// K2: per-bucket totals via LDS histogram (196 global atomics per block)
__global__ void bucket_count_kernel(const int* __restrict__ col, int* __restrict__ colTot) {
    __shared__ int h[NB];
    for (int i = threadIdx.x; i < NB; i += 256) h[i] = 0;
    __syncthreads();
    int e0 = blockIdx.x * CHK, e1 = min(e0 + CHK, E_EDGES);
    for (int e = e0 + threadIdx.x; e < e1; e += 256)
        atomicAdd(&h[col[e] >> 8], 1);
    __syncthreads();
    for (int i = threadIdx.x; i < NB; i += 256)
        if (h[i]) atomicAdd(&colTot[i], h[i]);
}

// K3: scan 196 bucket totals -> bucketStart[NB+1]; init global cursors.
__global__ void bucket_scan_kernel(const int* __restrict__ colTot,
                                   int* __restrict__ bucketStart, int* __restrict__ cursor) {
    __shared__ int sc[256];
    int t = threadIdx.x;
    sc[t] = (t < NB) ? colTot[t] : 0;
    __syncthreads();
    for (int off = 1; off < 256; off <<= 1) {
        int v = sc[t];
        int a = (t >= off) ? sc[t - off] : 0;
        __syncthreads();
        sc[t] = v + a;
        __syncthreads();
    }
    int base = (t == 0) ? 0 : sc[t - 1];
    if (t < NB) { bucketStart[t] = base; cursor[t] = base; }
    if (t == NB - 1) bucketStart[NB] = sc[t];
}

// K4: partition edges into bucket-contiguous staging S (packed (row<<8)|(col&255));
// range-claim per (chunk,bucket) via global cursor; fold deg histogram.
__global__ void partition_kernel(const int* __restrict__ row, const int* __restrict__ col,
                                 int* __restrict__ cursor, u32* __restrict__ S,
                                 int* __restrict__ deg) {
    __shared__ int h[NB], base[NB];
    int p = blockIdx.x;
    for (int i = threadIdx.x; i < NB; i += 256) h[i] = 0;
    __syncthreads();
    int e0 = p * CHK, e1 = min(e0 + CHK, E_EDGES);
    for (int e = e0 + threadIdx.x; e < e1; e += 256)
        atomicAdd(&h[col[e] >> 8], 1);
    __syncthreads();
    for (int i = threadIdx.x; i < NB; i += 256)
        base[i] = h[i] ? atomicAdd(&cursor[i], h[i]) : 0;
    __syncthreads();
    for (int i = threadIdx.x; i < NB; i += 256) h[i] = 0;   // reuse as local cursor
    __syncthreads();
    for (int e = e0 + threadIdx.x; e < e1; e += 256) {
        int r = row[e], c = col[e];
        atomicAdd(&deg[r], 1);
        int b = c >> 8;
        int pos = base[b] + atomicAdd(&h[b], 1);
        S[pos] = ((u32)r << 8) | (u32)(c & 255);
    }
}

// K5: per-bucket fine CSR: 256-col LDS hist + scan -> start[]; place srcrow (u16).
__global__ void fine_csr_kernel(const u32* __restrict__ S,
                                const int* __restrict__ bucketStart,
                                int* __restrict__ start, u16* __restrict__ srcrow) {
    __shared__ int h[CPB], cur[CPB], sc[CPB];
    int b = blockIdx.x, t = threadIdx.x;
    h[t] = 0;
    __syncthreads();
    int e0 = bucketStart[b], e1 = bucketStart[b + 1];
    for (int e = e0 + t; e < e1; e += 256) atomicAdd(&h[S[e] & 255u], 1);
    __syncthreads();
    sc[t] = h[t];
    __syncthreads();
    for (int off = 1; off < 256; off <<= 1) {
        int v = sc[t];
        int a = (t >= off) ? sc[t - off] : 0;
        __syncthreads();
        sc[t] = v + a;
        __syncthreads();
    }
    int base = (t == 0) ? 0 : sc[t - 1];
    int gcol = b * CPB + t;
    if (gcol < N_NODES) start[gcol] = e0 + base;
    if (b == NB - 1 && t == 0) start[N_NODES] = E_EDGES;
    cur[t] = base;
    __syncthreads();
    for (int e = e0 + t; e < e1; e += 256) {
        u32 v = S[e];
        int pos = atomicAdd(&cur[v & 255u], 1);
        srcrow[e0 + pos] = (u16)(v >> 8);
    }
}

// K6a/b/c: group nodes by label
__global__ void label_hist_kernel(const int* __restrict__ label, int* __restrict__ labCnt) {
    __shared__ int h[8];
    if (threadIdx.x < 8) h[threadIdx.x] = 0;
    __syncthreads();
    int n = blockIdx.x * 256 + threadIdx.x;
    if (n < N_NODES) atomicAdd(&h[label[n]], 1);
    __syncthreads();
    if (threadIdx.x < 8 && h[threadIdx.x] > 0) atomicAdd(&labCnt[threadIdx.x], h[threadIdx.x]);
}
__global__ void label_base_kernel(const int* __restrict__ labCnt, int* __restrict__ labCur) {
    if (threadIdx.x == 0) {
        int run = 0;
        for (int i = 0; i < 8; ++i) { labCur[i] = run; run += labCnt[i]; }
    }
}
__global__ void label_fill_kernel(const int* __restrict__ label, int* __restrict__ labCur,
                                  int* __restrict__ nodeByLabel) {
    __shared__ int h[8], base[8], c2[8];
    int t = threadIdx.x;
    if (t < 8) { h[t] = 0; c2[t] = 0; }
    __syncthreads();
    int n = blockIdx.x * 256 + t;
    int l = 0;
    if (n < N_NODES) { l = label[n]; atomicAdd(&h[l], 1); }
    __syncthreads();
    if (t < 8 && h[t] > 0) base[t] = atomicAdd(&labCur[t], h[t]);
    __syncthreads();
    if (n < N_NODES) {
        int pos = base[l] + atomicAdd(&c2[l], 1);
        nodeByLabel[pos] = n;
    }
}

// K7: label-grouped node transform -> bf16 messages.
//   x1 = x + cnt*(x@W); ox = x1 + (L>0 ? x1@Wid[L-1] : 0); msg = dinv*ox (bf16)
__global__ void node_msg_kernel(const float* __restrict__ x,
                                const int* __restrict__ cnt,
                                const int* __restrict__ label,
                                const int* __restrict__ deg,
                                const float* __restrict__ W,
                                const float* __restrict__ Wid,
                                const int* __restrict__ nodeByLabel,
                                __hip_bfloat16* __restrict__ msgb) {
    __shared__ float xs[GB][C_DIM];
    __shared__ int nid[GB], lab[GB], cc[GB];
    int t = threadIdx.x;
    if (t < GB) {
        int n = nodeByLabel[blockIdx.x * GB + t];
        nid[t] = n; lab[t] = label[n]; cc[t] = cnt[n];
    }
    __syncthreads();
    #pragma unroll
    for (int g = 0; g < GB; ++g)
        xs[g][t] = x[(size_t)nid[g] * C_DIM + t];
    __syncthreads();
    for (int g = 0; g < GB; ++g) {          // ego update (~4% of nodes)
        int c = cc[g];
        if (c > 0) {
            float acc = 0.f;
            #pragma unroll 8
            for (int k = 0; k < C_DIM; ++k) acc += xs[g][k] * W[k * C_DIM + t];
            __syncthreads();
            xs[g][t] += (float)c * acc;
            __syncthreads();
        }
    }
    float res[GB];
    #pragma unroll
    for (int g = 0; g < GB; ++g) res[g] = xs[g][t];
    if (lab[0] == lab[GB - 1]) {
        int L = lab[0];
        if (L > 0) {
            const float* Wl = Wid + (size_t)(L - 1) * C_DIM * C_DIM;
            float acc[GB];
            #pragma unroll
            for (int g = 0; g < GB; ++g) acc[g] = 0.f;
            for (int k = 0; k < C_DIM; ++k) {
                float w = Wl[k * C_DIM + t];
                #pragma unroll
                for (int g = 0; g < GB; ++g) acc[g] += xs[g][k] * w;
            }
            #pragma unroll
            for (int g = 0; g < GB; ++g) res[g] += acc[g];
        }
    } else {
        for (int g = 0; g < GB; ++g) {
            int L = lab[g];
            if (L > 0) {
                const float* Wl = Wid + (size_t)(L - 1) * C_DIM * C_DIM;
                float acc = 0.f;
                #pragma unroll 8
                for (int k = 0; k < C_DIM; ++k) acc += xs[g][k] * Wl[k * C_DIM + t];
                res[g] += acc;
            }
        }
    }
    #pragma unroll
    for (int g = 0; g < GB; ++g) {
        int n = nid[g];
        float di = rsqrtf((float)(deg[n] + 1));
        msgb[(size_t)n * C_DIM + t] = __float2bfloat16(di * res[g]);
    }
}

// K8: gather + finalize. One wave per dest node; lane owns channel pair (2 bf16 = 1 dword).
__global__ void gather_kernel(const int* __restrict__ start,
                              const u16* __restrict__ srcrow,
                              const int* __restrict__ deg,
                              const u32* __restrict__ m32,   // bf16x2-packed msg
                              float* __restrict__ out) {
    int wid  = threadIdx.x >> 6;
    int lane = threadIdx.x & 63;
    int c = blockIdx.x * 4 + wid;
    int e0 = start[c], e1 = start[c + 1];
    u32 u = m32[(size_t)c * 64 + lane];                       // self-loop message
    float a0 = __uint_as_float(u << 16);
    float a1 = __uint_as_float(u & 0xffff0000u);
    int e = e0;
    for (; e + 4 <= e1; e += 4) {
        int r0 = srcrow[e], r1 = srcrow[e + 1], r2 = srcrow[e + 2], r3 = srcrow[e + 3];
        u32 u0 = m32[(size_t)r0 * 64 + lane];
        u32 u1 = m32[(size_t)r1 * 64 + lane];
        u32 u2 = m32[(size_t)r2 * 64 + lane];
        u32 u3 = m32[(size_t)r3 * 64 + lane];
        a0 += __uint_as_float(u0 << 16) + __uint_as_float(u1 << 16)
            + __uint_as_float(u2 << 16) + __uint_as_float(u3 << 16);
        a1 += __uint_as_float(u0 & 0xffff0000u) + __uint_as_float(u1 & 0xffff0000u)
            + __uint_as_float(u2 & 0xffff0000u) + __uint_as_float(u3 & 0xffff0000u);
    }
    for (; e < e1; ++e) {
        u32 ue = m32[(size_t)srcrow[e] * 64 + lane];
        a0 += __uint_as_float(ue << 16);
        a1 += __uint_as_float(ue & 0xffff0000u);
    }
    float di = rsqrtf((float)(deg[c] + 1));
    ((float2*)out)[(size_t)c * 64 + lane] = make_float2(di * a0, di * a1);
}

extern "C" void kernel_launch(void* const* d_in, const int* in_sizes, int n_in,
                              void* d_out, int out_size, void* d_ws, size_t ws_size,
                              hipStream_t stream) {
    const float* x     = (const float*)d_in[0];
    const int*   edge  = (const int*)d_in[1];   // [2][E]
    const int*   id    = (const int*)d_in[2];
    const int*   label = (const int*)d_in[3];
    const float* W     = (const float*)d_in[4];
    const float* Wid   = (const float*)d_in[5];
    float*       out   = (float*)d_out;

    const int* row = edge;
    const int* col = edge + E_EDGES;

    // ws layout:
    // msgb[N*C] bf16 | S[E] u32 | srcrow[E] u16 | start[N+1] | bucketStart[NB+1] |
    // cursor[NB] | nodeByLabel[N] | ZERO-REGION{ cnt[N] | deg[N] | colTot[NB] | labCnt[8] | labCur[8] }
    __hip_bfloat16* msgb = (__hip_bfloat16*)d_ws;
    u32* S           = (u32*)(msgb + (size_t)N_NODES * C_DIM);
    u16* srcrow      = (u16*)(S + E_EDGES);
    int* start       = (int*)(srcrow + E_EDGES);
    int* bucketStart = start + (N_NODES + 1);
    int* cursor      = bucketStart + (NB + 1);
    int* nodeByLabel = cursor + NB;
    int* cnt         = nodeByLabel + N_NODES;
    int* deg         = cnt + N_NODES;
    int* colTot      = deg + N_NODES;
    int* labCnt      = colTot + NB;
    int* labCur      = labCnt + 8;

    hipMemsetAsync(cnt, 0, (2 * (size_t)N_NODES + NB + 16) * sizeof(int), stream);

    hist_id_kernel     <<<(NUM_IDX + 255) / 256, 256, 0, stream>>>(id, cnt);
    bucket_count_kernel<<<NP, 256, 0, stream>>>(col, colTot);
    bucket_scan_kernel <<<1, 256, 0, stream>>>(colTot, bucketStart, cursor);
    partition_kernel   <<<NP, 256, 0, stream>>>(row, col, cursor, S, deg);
    fine_csr_kernel    <<<NB, 256, 0, stream>>>(S, bucketStart, start, srcrow);
    label_hist_kernel  <<<(N_NODES + 255) / 256, 256, 0, stream>>>(label, labCnt);
    label_base_kernel  <<<1, 64, 0, stream>>>(labCnt, labCur);
    label_fill_kernel  <<<(N_NODES + 255) / 256, 256, 0, stream>>>(label, labCur, nodeByLabel);
    node_msg_kernel    <<<N_NODES / GB, C_DIM, 0, stream>>>(x, cnt, label, deg, W, Wid,
                                                            nodeByLabel, msgb);
    gather_kernel      <<<N_NODES / 4, 256, 0, stream>>>(start, srcrow, deg,
                                                         (const u32*)msgb, out);
}

// Round 6
// 322.002 us; speedup vs baseline: 2.9503x; 1.0131x over previous
//
#include <hip/hip_runtime.h>
#include <hip/hip_bf16.h>

typedef unsigned int   u32;
typedef unsigned short u16;

#define N_NODES 50000
#define C_DIM   128
#define E_EDGES 1600000
#define NUM_IDX 2048

#define CPB 256                    // cols per coarse bucket (col >> 8)
#define NB  196                    // ceil(N/CPB)
#define CHK 4096                   // edges per chunk
#define NP  391                    // ceil(E/CHK)
#define PT  512                    // threads for partition-family kernels
#define GB  8                      // nodes per label-matmul block

// K1: multiplicity histogram of `id` -> cnt[N]
__global__ void hist_id_kernel(const int* __restrict__ id, int* __restrict__ cnt) {
    int i = blockIdx.x * blockDim.x + threadIdx.x;
    if (i < NUM_IDX) atomicAdd(&cnt[id[i]], 1);
}

// K2: coarse col-bucket totals (LDS hist) + out-degree histogram
__global__ void bucket_count_kernel(const int* __restrict__ row, const int* __restrict__ col,
                                    int* __restrict__ colTot, int* __restrict__ deg) {
    __shared__ int h[NB];
    for (int i = threadIdx.x; i < NB; i += PT) h[i] = 0;
    __syncthreads();
    int e0 = blockIdx.x * CHK, e1 = min(e0 + CHK, E_EDGES);
    for (int e = e0 + threadIdx.x; e < e1; e += PT) {
        atomicAdd(&h[col[e] >> 8], 1);
        atomicAdd(&deg[row[e]], 1);
    }
    __syncthreads();
    for (int i = threadIdx.x; i < NB; i += PT)
        if (h[i]) atomicAdd(&colTot[i], h[i]);
}

// K3: scan 196 bucket totals -> bucketStart[NB+1]; init global cursors.
__global__ void bucket_scan_kernel(const int* __restrict__ colTot,
                                   int* __restrict__ bucketStart, int* __restrict__ cursor) {
    __shared__ int sc[256];
    int t = threadIdx.x;
    sc[t] = (t < NB) ? colTot[t] : 0;
    __syncthreads();
    for (int off = 1; off < 256; off <<= 1) {
        int v = sc[t];
        int a = (t >= off) ? sc[t - off] : 0;
        __syncthreads();
        sc[t] = v + a;
        __syncthreads();
    }
    int base = (t == 0) ? 0 : sc[t - 1];
    if (t < NB) { bucketStart[t] = base; cursor[t] = base; }
    if (t == NB - 1) bucketStart[NB] = sc[t];
}

// K4: partition edges into bucket-contiguous staging S (packed (row<<8)|(col&255));
// per-(chunk,bucket) range claim via global cursor.
__global__ void partition_kernel(const int* __restrict__ row, const int* __restrict__ col,
                                 int* __restrict__ cursor, u32* __restrict__ S) {
    __shared__ int h[NB], base[NB];
    int e0 = blockIdx.x * CHK, e1 = min(e0 + CHK, E_EDGES);
    for (int i = threadIdx.x; i < NB; i += PT) h[i] = 0;
    __syncthreads();
    for (int e = e0 + threadIdx.x; e < e1; e += PT)
        atomicAdd(&h[col[e] >> 8], 1);
    __syncthreads();
    for (int i = threadIdx.x; i < NB; i += PT)
        base[i] = h[i] ? atomicAdd(&cursor[i], h[i]) : 0;
    __syncthreads();
    for (int i = threadIdx.x; i < NB; i += PT) h[i] = 0;   // reuse as local cursor
    __syncthreads();
    for (int e = e0 + threadIdx.x; e < e1; e += PT) {
        int r = row[e], c = col[e];
        int b = c >> 8;
        int pos = base[b] + atomicAdd(&h[b], 1);
        S[pos] = ((u32)r << 8) | (u32)(c & 255);
    }
}

// K5: per-bucket fine CSR: 256-col LDS hist + scan -> start[]; place srcrow (u16).
__global__ void fine_csr_kernel(const u32* __restrict__ S,
                                const int* __restrict__ bucketStart,
                                int* __restrict__ start, u16* __restrict__ srcrow) {
    __shared__ int h[CPB], cur[CPB], sc[CPB];
    int b = blockIdx.x, t = threadIdx.x;
    if (t < CPB) h[t] = 0;
    __syncthreads();
    int e0 = bucketStart[b], e1 = bucketStart[b + 1];
    for (int e = e0 + t; e < e1; e += PT) atomicAdd(&h[S[e] & 255u], 1);
    __syncthreads();
    if (t < CPB) sc[t] = h[t];
    __syncthreads();
    for (int off = 1; off < CPB; off <<= 1) {
        int v = 0, a = 0;
        if (t < CPB) { v = sc[t]; a = (t >= off) ? sc[t - off] : 0; }
        __syncthreads();
        if (t < CPB) sc[t] = v + a;
        __syncthreads();
    }
    if (t < CPB) {
        int base = (t == 0) ? 0 : sc[t - 1];
        int gcol = b * CPB + t;
        if (gcol < N_NODES) start[gcol] = e0 + base;
        cur[t] = base;
    }
    if (b == NB - 1 && t == 0) start[N_NODES] = E_EDGES;
    __syncthreads();
    for (int e = e0 + t; e < e1; e += PT) {
        u32 v = S[e];
        int pos = atomicAdd(&cur[v & 255u], 1);
        srcrow[e0 + pos] = (u16)(v >> 8);
    }
}

// K6a/b/c: group nodes by label
__global__ void label_hist_kernel(const int* __restrict__ label, int* __restrict__ labCnt) {
    __shared__ int h[8];
    if (threadIdx.x < 8) h[threadIdx.x] = 0;
    __syncthreads();
    int n = blockIdx.x * 256 + threadIdx.x;
    if (n < N_NODES) atomicAdd(&h[label[n]], 1);
    __syncthreads();
    if (threadIdx.x < 8 && h[threadIdx.x] > 0) atomicAdd(&labCnt[threadIdx.x], h[threadIdx.x]);
}
__global__ void label_base_kernel(const int* __restrict__ labCnt, int* __restrict__ labCur) {
    if (threadIdx.x == 0) {
        int run = 0;
        for (int i = 0; i < 8; ++i) { labCur[i] = run; run += labCnt[i]; }
    }
}
__global__ void label_fill_kernel(const int* __restrict__ label, int* __restrict__ labCur,
                                  int* __restrict__ nodeByLabel) {
    __shared__ int h[8], base[8], c2[8];
    int t = threadIdx.x;
    if (t < 8) { h[t] = 0; c2[t] = 0; }
    __syncthreads();
    int n = blockIdx.x * 256 + t;
    int l = 0;
    if (n < N_NODES) { l = label[n]; atomicAdd(&h[l], 1); }
    __syncthreads();
    if (t < 8 && h[t] > 0) base[t] = atomicAdd(&labCur[t], h[t]);
    __syncthreads();
    if (n < N_NODES) {
        int pos = base[l] + atomicAdd(&c2[l], 1);
        nodeByLabel[pos] = n;
    }
}

// K7: label-grouped node transform -> bf16 messages.
//   x1 = x + cnt*(x@W); ox = x1 + (L>0 ? x1@Wid[L-1] : 0); msg = dinv*ox (bf16)
__global__ void node_msg_kernel(const float* __restrict__ x,
                                const int* __restrict__ cnt,
                                const int* __restrict__ label,
                                const int* __restrict__ deg,
                                const float* __restrict__ W,
                                const float* __restrict__ Wid,
                                const int* __restrict__ nodeByLabel,
                                __hip_bfloat16* __restrict__ msgb) {
    __shared__ float xs[GB][C_DIM];
    __shared__ int nid[GB], lab[GB], cc[GB];
    int t = threadIdx.x;
    if (t < GB) {
        int n = nodeByLabel[blockIdx.x * GB + t];
        nid[t] = n; lab[t] = label[n]; cc[t] = cnt[n];
    }
    __syncthreads();
    #pragma unroll
    for (int g = 0; g < GB; ++g)
        xs[g][t] = x[(size_t)nid[g] * C_DIM + t];
    __syncthreads();
    for (int g = 0; g < GB; ++g) {          // ego update (~4% of nodes)
        int c = cc[g];
        if (c > 0) {
            float acc = 0.f;
            #pragma unroll 8
            for (int k = 0; k < C_DIM; ++k) acc += xs[g][k] * W[k * C_DIM + t];
            __syncthreads();
            xs[g][t] += (float)c * acc;
            __syncthreads();
        }
    }
    float res[GB];
    #pragma unroll
    for (int g = 0; g < GB; ++g) res[g] = xs[g][t];
    if (lab[0] == lab[GB - 1]) {
        int L = lab[0];
        if (L > 0) {
            const float* Wl = Wid + (size_t)(L - 1) * C_DIM * C_DIM;
            float acc[GB];
            #pragma unroll
            for (int g = 0; g < GB; ++g) acc[g] = 0.f;
            for (int k = 0; k < C_DIM; ++k) {
                float w = Wl[k * C_DIM + t];
                #pragma unroll
                for (int g = 0; g < GB; ++g) acc[g] += xs[g][k] * w;
            }
            #pragma unroll
            for (int g = 0; g < GB; ++g) res[g] += acc[g];
        }
    } else {
        for (int g = 0; g < GB; ++g) {
            int L = lab[g];
            if (L > 0) {
                const float* Wl = Wid + (size_t)(L - 1) * C_DIM * C_DIM;
                float acc = 0.f;
                #pragma unroll 8
                for (int k = 0; k < C_DIM; ++k) acc += xs[g][k] * Wl[k * C_DIM + t];
                res[g] += acc;
            }
        }
    }
    #pragma unroll
    for (int g = 0; g < GB; ++g) {
        int n = nid[g];
        float di = rsqrtf((float)(deg[n] + 1));
        msgb[(size_t)n * C_DIM + t] = __float2bfloat16(di * res[g]);
    }
}

// K8: gather + finalize. One wave per dest node; lane owns channel pair (2 bf16 = 1 dword).
__global__ void gather_kernel(const int* __restrict__ start,
                              const u16* __restrict__ srcrow,
                              const int* __restrict__ deg,
                              const u32* __restrict__ m32,   // bf16x2-packed msg
                              float* __restrict__ out) {
    int wid  = threadIdx.x >> 6;
    int lane = threadIdx.x & 63;
    int c = blockIdx.x * 4 + wid;
    int e0 = start[c], e1 = start[c + 1];
    u32 u = m32[(size_t)c * 64 + lane];                       // self-loop message
    float a0 = __uint_as_float(u << 16);
    float a1 = __uint_as_float(u & 0xffff0000u);
    int e = e0;
    for (; e + 4 <= e1; e += 4) {
        int r0 = srcrow[e], r1 = srcrow[e + 1], r2 = srcrow[e + 2], r3 = srcrow[e + 3];
        u32 u0 = m32[(size_t)r0 * 64 + lane];
        u32 u1 = m32[(size_t)r1 * 64 + lane];
        u32 u2 = m32[(size_t)r2 * 64 + lane];
        u32 u3 = m32[(size_t)r3 * 64 + lane];
        a0 += __uint_as_float(u0 << 16) + __uint_as_float(u1 << 16)
            + __uint_as_float(u2 << 16) + __uint_as_float(u3 << 16);
        a1 += __uint_as_float(u0 & 0xffff0000u) + __uint_as_float(u1 & 0xffff0000u)
            + __uint_as_float(u2 & 0xffff0000u) + __uint_as_float(u3 & 0xffff0000u);
    }
    for (; e < e1; ++e) {
        u32 ue = m32[(size_t)srcrow[e] * 64 + lane];
        a0 += __uint_as_float(ue << 16);
        a1 += __uint_as_float(ue & 0xffff0000u);
    }
    float di = rsqrtf((float)(deg[c] + 1));
    ((float2*)out)[(size_t)c * 64 + lane] = make_float2(di * a0, di * a1);
}

extern "C" void kernel_launch(void* const* d_in, const int* in_sizes, int n_in,
                              void* d_out, int out_size, void* d_ws, size_t ws_size,
                              hipStream_t stream) {
    const float* x     = (const float*)d_in[0];
    const int*   edge  = (const int*)d_in[1];   // [2][E]
    const int*   id    = (const int*)d_in[2];
    const int*   label = (const int*)d_in[3];
    const float* W     = (const float*)d_in[4];
    const float* Wid   = (const float*)d_in[5];
    float*       out   = (float*)d_out;

    const int* row = edge;
    const int* col = edge + E_EDGES;

    // ws layout:
    // msgb[N*C] bf16 | S[E] u32 | srcrow[E] u16 | start[N+1] | bucketStart[NB+1] |
    // cursor[NB] | nodeByLabel[N] | ZERO{ cnt[N] | deg[N] | colTot[NB] | labCnt[8] | labCur[8] }
    __hip_bfloat16* msgb = (__hip_bfloat16*)d_ws;
    u32* S           = (u32*)(msgb + (size_t)N_NODES * C_DIM);
    u16* srcrow      = (u16*)(S + E_EDGES);
    int* start       = (int*)(srcrow + E_EDGES);
    int* bucketStart = start + (N_NODES + 1);
    int* cursor      = bucketStart + (NB + 1);
    int* nodeByLabel = cursor + NB;
    int* cnt         = nodeByLabel + N_NODES;
    int* deg         = cnt + N_NODES;
    int* colTot      = deg + N_NODES;
    int* labCnt      = colTot + NB;
    int* labCur      = labCnt + 8;

    hipMemsetAsync(cnt, 0, (2 * (size_t)N_NODES + NB + 16) * sizeof(int), stream);

    hist_id_kernel     <<<(NUM_IDX + 255) / 256, 256, 0, stream>>>(id, cnt);
    bucket_count_kernel<<<NP, PT, 0, stream>>>(row, col, colTot, deg);
    bucket_scan_kernel <<<1, 256, 0, stream>>>(colTot, bucketStart, cursor);
    partition_kernel   <<<NP, PT, 0, stream>>>(row, col, cursor, S);
    fine_csr_kernel    <<<NB, PT, 0, stream>>>(S, bucketStart, start, srcrow);
    label_hist_kernel  <<<(N_NODES + 255) / 256, 256, 0, stream>>>(label, labCnt);
    label_base_kernel  <<<1, 64, 0, stream>>>(labCnt, labCur);
    label_fill_kernel  <<<(N_NODES + 255) / 256, 256, 0, stream>>>(label, labCur, nodeByLabel);
    node_msg_kernel    <<<N_NODES / GB, C_DIM, 0, stream>>>(x, cnt, label, deg, W, Wid,
                                                            nodeByLabel, msgb);
    gather_kernel      <<<N_NODES / 4, 256, 0, stream>>>(start, srcrow, deg,
                                                         (const u32*)msgb, out);
}

// Round 7
// 276.768 us; speedup vs baseline: 3.4324x; 1.1634x over previous
//
#include <hip/hip_runtime.h>
#include <hip/hip_bf16.h>

typedef unsigned int   u32;
typedef unsigned short u16;
typedef unsigned char  u8;

#define N_NODES 50000
#define C_DIM   128
#define E_EDGES 1600000
#define NUM_IDX 2048

#define CPB 256                    // cols per coarse bucket (key >> 8)
#define NB  196                    // ceil(N/CPB)
#define CHK 4096                   // edges per chunk
#define NP  391                    // ceil(E/CHK)
#define PT  512                    // threads for partition-family kernels
#define GB  8                      // nodes per label-matmul block

// K1: multiplicity histogram of `id` -> cnt[N]
__global__ void hist_id_kernel(const int* __restrict__ id, int* __restrict__ cnt) {
    int i = blockIdx.x * blockDim.x + threadIdx.x;
    if (i < NUM_IDX) atomicAdd(&cnt[id[i]], 1);
}

// K2: coarse bucket totals for col AND row (LDS hist; 2*196 global atomics/block)
__global__ void bucket_count_kernel(const int* __restrict__ row, const int* __restrict__ col,
                                    int* __restrict__ colTot, int* __restrict__ rowTot) {
    __shared__ int hc[NB], hr[NB];
    for (int i = threadIdx.x; i < NB; i += PT) { hc[i] = 0; hr[i] = 0; }
    __syncthreads();
    int e0 = blockIdx.x * CHK, e1 = min(e0 + CHK, E_EDGES);
    for (int e = e0 + threadIdx.x; e < e1; e += PT) {
        atomicAdd(&hc[col[e] >> 8], 1);
        atomicAdd(&hr[row[e] >> 8], 1);
    }
    __syncthreads();
    for (int i = threadIdx.x; i < NB; i += PT) {
        if (hc[i]) atomicAdd(&colTot[i], hc[i]);
        if (hr[i]) atomicAdd(&rowTot[i], hr[i]);
    }
}

// K3: scan both 196-entry tables -> starts + cursors
__global__ void bucket_scan_kernel(const int* __restrict__ colTot, const int* __restrict__ rowTot,
                                   int* __restrict__ bucketStart, int* __restrict__ cursor,
                                   int* __restrict__ rowStart, int* __restrict__ rowCursor) {
    __shared__ int sc[256];
    int t = threadIdx.x;
    // --- col ---
    sc[t] = (t < NB) ? colTot[t] : 0;
    __syncthreads();
    for (int off = 1; off < 256; off <<= 1) {
        int v = sc[t];
        int a = (t >= off) ? sc[t - off] : 0;
        __syncthreads();
        sc[t] = v + a;
        __syncthreads();
    }
    if (t < NB) {
        int base = (t == 0) ? 0 : sc[t - 1];
        bucketStart[t] = base; cursor[t] = base;
        if (t == NB - 1) bucketStart[NB] = sc[t];
    }
    __syncthreads();
    // --- row ---
    sc[t] = (t < NB) ? rowTot[t] : 0;
    __syncthreads();
    for (int off = 1; off < 256; off <<= 1) {
        int v = sc[t];
        int a = (t >= off) ? sc[t - off] : 0;
        __syncthreads();
        sc[t] = v + a;
        __syncthreads();
    }
    if (t < NB) {
        int base = (t == 0) ? 0 : sc[t - 1];
        rowStart[t] = base; rowCursor[t] = base;
        if (t == NB - 1) rowStart[NB] = sc[t];
    }
}

// K4: partition edges: S (col-keyed, packed (row<<8)|(col&255)) and Sr (row-keyed, u8 row&255)
__global__ void partition_kernel(const int* __restrict__ row, const int* __restrict__ col,
                                 int* __restrict__ cursor, int* __restrict__ rowCursor,
                                 u32* __restrict__ S, u8* __restrict__ Sr) {
    __shared__ int hc[NB], basec[NB], hr[NB], baser[NB];
    int e0 = blockIdx.x * CHK, e1 = min(e0 + CHK, E_EDGES);
    for (int i = threadIdx.x; i < NB; i += PT) { hc[i] = 0; hr[i] = 0; }
    __syncthreads();
    for (int e = e0 + threadIdx.x; e < e1; e += PT) {
        atomicAdd(&hc[col[e] >> 8], 1);
        atomicAdd(&hr[row[e] >> 8], 1);
    }
    __syncthreads();
    for (int i = threadIdx.x; i < NB; i += PT) {
        basec[i] = hc[i] ? atomicAdd(&cursor[i], hc[i]) : 0;
        baser[i] = hr[i] ? atomicAdd(&rowCursor[i], hr[i]) : 0;
    }
    __syncthreads();
    for (int i = threadIdx.x; i < NB; i += PT) { hc[i] = 0; hr[i] = 0; }  // local cursors
    __syncthreads();
    for (int e = e0 + threadIdx.x; e < e1; e += PT) {
        int r = row[e], c = col[e];
        int bc = c >> 8;
        int pc = basec[bc] + atomicAdd(&hc[bc], 1);
        S[pc] = ((u32)r << 8) | (u32)(c & 255);
        int br = r >> 8;
        int pr = baser[br] + atomicAdd(&hr[br], 1);
        Sr[pr] = (u8)(r & 255);
    }
}

// K5: per row-bucket LDS histogram of Sr -> dinv[n] = rsqrt(outdeg+1). Zero atomics.
__global__ void deg_kernel(const u8* __restrict__ Sr, const int* __restrict__ rowStart,
                           float* __restrict__ dinv) {
    __shared__ int h[CPB];
    int b = blockIdx.x, t = threadIdx.x;
    if (t < CPB) h[t] = 0;
    __syncthreads();
    int e0 = rowStart[b], e1 = rowStart[b + 1];
    for (int e = e0 + t; e < e1; e += PT) atomicAdd(&h[Sr[e]], 1);
    __syncthreads();
    if (t < CPB) {
        int n = b * CPB + t;
        if (n < N_NODES) dinv[n] = rsqrtf((float)(h[t] + 1));
    }
}

// K6: per-bucket fine CSR: 256-col LDS hist + scan -> start[]; place srcrow (u16).
__global__ void fine_csr_kernel(const u32* __restrict__ S,
                                const int* __restrict__ bucketStart,
                                int* __restrict__ start, u16* __restrict__ srcrow) {
    __shared__ int h[CPB], cur[CPB], sc[CPB];
    int b = blockIdx.x, t = threadIdx.x;
    if (t < CPB) h[t] = 0;
    __syncthreads();
    int e0 = bucketStart[b], e1 = bucketStart[b + 1];
    for (int e = e0 + t; e < e1; e += PT) atomicAdd(&h[S[e] & 255u], 1);
    __syncthreads();
    if (t < CPB) sc[t] = h[t];
    __syncthreads();
    for (int off = 1; off < CPB; off <<= 1) {
        int v = 0, a = 0;
        if (t < CPB) { v = sc[t]; a = (t >= off) ? sc[t - off] : 0; }
        __syncthreads();
        if (t < CPB) sc[t] = v + a;
        __syncthreads();
    }
    if (t < CPB) {
        int base = (t == 0) ? 0 : sc[t - 1];
        int gcol = b * CPB + t;
        if (gcol < N_NODES) start[gcol] = e0 + base;
        cur[t] = base;
    }
    if (b == NB - 1 && t == 0) start[N_NODES] = E_EDGES;
    __syncthreads();
    for (int e = e0 + t; e < e1; e += PT) {
        u32 v = S[e];
        int pos = atomicAdd(&cur[v & 255u], 1);
        srcrow[e0 + pos] = (u16)(v >> 8);
    }
}

// K7a/b/c: group nodes by label
__global__ void label_hist_kernel(const int* __restrict__ label, int* __restrict__ labCnt) {
    __shared__ int h[8];
    if (threadIdx.x < 8) h[threadIdx.x] = 0;
    __syncthreads();
    int n = blockIdx.x * 256 + threadIdx.x;
    if (n < N_NODES) atomicAdd(&h[label[n]], 1);
    __syncthreads();
    if (threadIdx.x < 8 && h[threadIdx.x] > 0) atomicAdd(&labCnt[threadIdx.x], h[threadIdx.x]);
}
__global__ void label_base_kernel(const int* __restrict__ labCnt, int* __restrict__ labCur) {
    if (threadIdx.x == 0) {
        int run = 0;
        for (int i = 0; i < 8; ++i) { labCur[i] = run; run += labCnt[i]; }
    }
}
__global__ void label_fill_kernel(const int* __restrict__ label, int* __restrict__ labCur,
                                  int* __restrict__ nodeByLabel) {
    __shared__ int h[8], base[8], c2[8];
    int t = threadIdx.x;
    if (t < 8) { h[t] = 0; c2[t] = 0; }
    __syncthreads();
    int n = blockIdx.x * 256 + t;
    int l = 0;
    if (n < N_NODES) { l = label[n]; atomicAdd(&h[l], 1); }
    __syncthreads();
    if (t < 8 && h[t] > 0) base[t] = atomicAdd(&labCur[t], h[t]);
    __syncthreads();
    if (n < N_NODES) {
        int pos = base[l] + atomicAdd(&c2[l], 1);
        nodeByLabel[pos] = n;
    }
}

// K8: label-grouped node transform -> bf16 messages.
__global__ void node_msg_kernel(const float* __restrict__ x,
                                const int* __restrict__ cnt,
                                const int* __restrict__ label,
                                const float* __restrict__ dinv,
                                const float* __restrict__ W,
                                const float* __restrict__ Wid,
                                const int* __restrict__ nodeByLabel,
                                __hip_bfloat16* __restrict__ msgb) {
    __shared__ float xs[GB][C_DIM];
    __shared__ int nid[GB], lab[GB], cc[GB];
    int t = threadIdx.x;
    if (t < GB) {
        int n = nodeByLabel[blockIdx.x * GB + t];
        nid[t] = n; lab[t] = label[n]; cc[t] = cnt[n];
    }
    __syncthreads();
    #pragma unroll
    for (int g = 0; g < GB; ++g)
        xs[g][t] = x[(size_t)nid[g] * C_DIM + t];
    __syncthreads();
    for (int g = 0; g < GB; ++g) {          // ego update (~4% of nodes)
        int c = cc[g];
        if (c > 0) {
            float acc = 0.f;
            #pragma unroll 8
            for (int k = 0; k < C_DIM; ++k) acc += xs[g][k] * W[k * C_DIM + t];
            __syncthreads();
            xs[g][t] += (float)c * acc;
            __syncthreads();
        }
    }
    float res[GB];
    #pragma unroll
    for (int g = 0; g < GB; ++g) res[g] = xs[g][t];
    if (lab[0] == lab[GB - 1]) {
        int L = lab[0];
        if (L > 0) {
            const float* Wl = Wid + (size_t)(L - 1) * C_DIM * C_DIM;
            float acc[GB];
            #pragma unroll
            for (int g = 0; g < GB; ++g) acc[g] = 0.f;
            for (int k = 0; k < C_DIM; ++k) {
                float w = Wl[k * C_DIM + t];
                #pragma unroll
                for (int g = 0; g < GB; ++g) acc[g] += xs[g][k] * w;
            }
            #pragma unroll
            for (int g = 0; g < GB; ++g) res[g] += acc[g];
        }
    } else {
        for (int g = 0; g < GB; ++g) {
            int L = lab[g];
            if (L > 0) {
                const float* Wl = Wid + (size_t)(L - 1) * C_DIM * C_DIM;
                float acc = 0.f;
                #pragma unroll 8
                for (int k = 0; k < C_DIM; ++k) acc += xs[g][k] * Wl[k * C_DIM + t];
                res[g] += acc;
            }
        }
    }
    #pragma unroll
    for (int g = 0; g < GB; ++g) {
        int n = nid[g];
        msgb[(size_t)n * C_DIM + t] = __float2bfloat16(dinv[n] * res[g]);
    }
}

// K9: gather + finalize. One wave per dest node; lane owns channel pair (2 bf16 = 1 dword).
__global__ void gather_kernel(const int* __restrict__ start,
                              const u16* __restrict__ srcrow,
                              const float* __restrict__ dinv,
                              const u32* __restrict__ m32,   // bf16x2-packed msg
                              float* __restrict__ out) {
    int wid  = threadIdx.x >> 6;
    int lane = threadIdx.x & 63;
    int c = blockIdx.x * 4 + wid;
    int e0 = start[c], e1 = start[c + 1];
    u32 u = m32[(size_t)c * 64 + lane];                       // self-loop message
    float a0 = __uint_as_float(u << 16);
    float a1 = __uint_as_float(u & 0xffff0000u);
    int e = e0;
    for (; e + 4 <= e1; e += 4) {
        int r0 = srcrow[e], r1 = srcrow[e + 1], r2 = srcrow[e + 2], r3 = srcrow[e + 3];
        u32 u0 = m32[(size_t)r0 * 64 + lane];
        u32 u1 = m32[(size_t)r1 * 64 + lane];
        u32 u2 = m32[(size_t)r2 * 64 + lane];
        u32 u3 = m32[(size_t)r3 * 64 + lane];
        a0 += __uint_as_float(u0 << 16) + __uint_as_float(u1 << 16)
            + __uint_as_float(u2 << 16) + __uint_as_float(u3 << 16);
        a1 += __uint_as_float(u0 & 0xffff0000u) + __uint_as_float(u1 & 0xffff0000u)
            + __uint_as_float(u2 & 0xffff0000u) + __uint_as_float(u3 & 0xffff0000u);
    }
    for (; e < e1; ++e) {
        u32 ue = m32[(size_t)srcrow[e] * 64 + lane];
        a0 += __uint_as_float(ue << 16);
        a1 += __uint_as_float(ue & 0xffff0000u);
    }
    float di = dinv[c];
    ((float2*)out)[(size_t)c * 64 + lane] = make_float2(di * a0, di * a1);
}

extern "C" void kernel_launch(void* const* d_in, const int* in_sizes, int n_in,
                              void* d_out, int out_size, void* d_ws, size_t ws_size,
                              hipStream_t stream) {
    const float* x     = (const float*)d_in[0];
    const int*   edge  = (const int*)d_in[1];   // [2][E]
    const int*   id    = (const int*)d_in[2];
    const int*   label = (const int*)d_in[3];
    const float* W     = (const float*)d_in[4];
    const float* Wid   = (const float*)d_in[5];
    float*       out   = (float*)d_out;

    const int* row = edge;
    const int* col = edge + E_EDGES;

    // ws layout:
    // msgb[N*C] bf16 | S[E] u32 | srcrow[E] u16 | Sr[E] u8 | start[N+1] |
    // bucketStart[NB+1] | cursor[NB] | rowStart[NB+1] | rowCursor[NB] |
    // nodeByLabel[N] | dinv[N] f32 | ZERO{ cnt[N] | colTot[NB] | rowTot[NB] | labCnt[8] | labCur[8] }
    __hip_bfloat16* msgb = (__hip_bfloat16*)d_ws;
    u32* S           = (u32*)(msgb + (size_t)N_NODES * C_DIM);
    u16* srcrow      = (u16*)(S + E_EDGES);
    u8*  Sr          = (u8*)(srcrow + E_EDGES);
    int* start       = (int*)(Sr + E_EDGES);
    int* bucketStart = start + (N_NODES + 1);
    int* cursor      = bucketStart + (NB + 1);
    int* rowStart    = cursor + NB;
    int* rowCursor   = rowStart + (NB + 1);
    int* nodeByLabel = rowCursor + NB;
    float* dinv      = (float*)(nodeByLabel + N_NODES);
    int* cnt         = (int*)(dinv + N_NODES);
    int* colTot      = cnt + N_NODES;
    int* rowTot      = colTot + NB;
    int* labCnt      = rowTot + NB;
    int* labCur      = labCnt + 8;

    hipMemsetAsync(cnt, 0, ((size_t)N_NODES + 2 * NB + 16) * sizeof(int), stream);

    hist_id_kernel     <<<(NUM_IDX + 255) / 256, 256, 0, stream>>>(id, cnt);
    bucket_count_kernel<<<NP, PT, 0, stream>>>(row, col, colTot, rowTot);
    bucket_scan_kernel <<<1, 256, 0, stream>>>(colTot, rowTot, bucketStart, cursor,
                                               rowStart, rowCursor);
    partition_kernel   <<<NP, PT, 0, stream>>>(row, col, cursor, rowCursor, S, Sr);
    deg_kernel         <<<NB, PT, 0, stream>>>(Sr, rowStart, dinv);
    fine_csr_kernel    <<<NB, PT, 0, stream>>>(S, bucketStart, start, srcrow);
    label_hist_kernel  <<<(N_NODES + 255) / 256, 256, 0, stream>>>(label, labCnt);
    label_base_kernel  <<<1, 64, 0, stream>>>(labCnt, labCur);
    label_fill_kernel  <<<(N_NODES + 255) / 256, 256, 0, stream>>>(label, labCur, nodeByLabel);
    node_msg_kernel    <<<N_NODES / GB, C_DIM, 0, stream>>>(x, cnt, label, dinv, W, Wid,
                                                            nodeByLabel, msgb);
    gather_kernel      <<<N_NODES / 4, 256, 0, stream>>>(start, srcrow, dinv,
                                                         (const u32*)msgb, out);
}

// Round 8
// 241.140 us; speedup vs baseline: 3.9396x; 1.1477x over previous
//
#include <hip/hip_runtime.h>
#include <hip/hip_bf16.h>

typedef unsigned int   u32;
typedef unsigned short u16;
typedef unsigned char  u8;
typedef float f32x2 __attribute__((ext_vector_type(2)));

#define N_NODES 50000
#define C_DIM   128
#define E_EDGES 1600000
#define NUM_IDX 2048

#define CPB 256                    // cols per coarse bucket (key >> 8)
#define NB  196                    // ceil(N/CPB)
#define CHK 4096                   // edges per chunk
#define NP  391                    // ceil(E/CHK)
#define PT  512                    // threads for partition-family kernels
#define GB  8                      // nodes per label-matmul block

// K1: label histogram (LDS-staged); blocks 0..7 also histogram `id` -> cnt[N]
__global__ void label_hist_kernel(const int* __restrict__ label, int* __restrict__ labCnt,
                                  const int* __restrict__ id, int* __restrict__ cnt) {
    __shared__ int h[8];
    if (threadIdx.x < 8) h[threadIdx.x] = 0;
    __syncthreads();
    int n = blockIdx.x * 256 + threadIdx.x;
    if (n < N_NODES) atomicAdd(&h[label[n]], 1);
    if (n < NUM_IDX) atomicAdd(&cnt[id[n]], 1);    // blocks 0..7 cover all 2048 ids
    __syncthreads();
    if (threadIdx.x < 8 && h[threadIdx.x] > 0) atomicAdd(&labCnt[threadIdx.x], h[threadIdx.x]);
}

// K2: per-chunk coarse histograms for col and row -> Hc[p][b], Hr[p][b]. No global atomics.
__global__ void chunk_hist_kernel(const int* __restrict__ row, const int* __restrict__ col,
                                  int* __restrict__ Hc, int* __restrict__ Hr) {
    __shared__ int hc[NB], hr[NB];
    int p = blockIdx.x;
    for (int i = threadIdx.x; i < NB; i += PT) { hc[i] = 0; hr[i] = 0; }
    __syncthreads();
    int e0 = p * CHK, e1 = min(e0 + CHK, E_EDGES);
    for (int e = e0 + threadIdx.x; e < e1; e += PT) {
        atomicAdd(&hc[col[e] >> 8], 1);
        atomicAdd(&hr[row[e] >> 8], 1);
    }
    __syncthreads();
    for (int i = threadIdx.x; i < NB; i += PT) {
        Hc[p * NB + i] = hc[i];
        Hr[p * NB + i] = hr[i];
    }
}

// K3: per-bucket scan across chunks: H[p][j] -> exclusive prefix (in place), tot[j].
// Block b<NB handles col-bucket b; block b>=NB handles row-bucket b-NB. NP<=PT.
__global__ void offsets_kernel(int* __restrict__ Hc, int* __restrict__ Hr,
                               int* __restrict__ colTot, int* __restrict__ rowTot) {
    __shared__ int sc[PT];
    int b = blockIdx.x;
    int j = (b < NB) ? b : b - NB;
    int* H   = (b < NB) ? Hc : Hr;
    int* tot = (b < NB) ? colTot : rowTot;
    int t = threadIdx.x;
    int v = (t < NP) ? H[t * NB + j] : 0;
    sc[t] = v;
    __syncthreads();
    for (int off = 1; off < PT; off <<= 1) {
        int a = (t >= off) ? sc[t - off] : 0;
        int s = sc[t];
        __syncthreads();
        sc[t] = s + a;
        __syncthreads();
    }
    if (t < NP) H[t * NB + j] = sc[t] - v;   // exclusive prefix within bucket
    if (t == PT - 1) tot[j] = sc[t];
}

// K4: scan bucket totals -> bucketStart/rowStart; also labCnt -> labCur bases.
__global__ void bucket_scan_kernel(const int* __restrict__ colTot, const int* __restrict__ rowTot,
                                   int* __restrict__ bucketStart, int* __restrict__ rowStart,
                                   const int* __restrict__ labCnt, int* __restrict__ labCur) {
    __shared__ int sc[256];
    int t = threadIdx.x;
    sc[t] = (t < NB) ? colTot[t] : 0;
    __syncthreads();
    for (int off = 1; off < 256; off <<= 1) {
        int v = sc[t];
        int a = (t >= off) ? sc[t - off] : 0;
        __syncthreads();
        sc[t] = v + a;
        __syncthreads();
    }
    if (t < NB) {
        bucketStart[t] = (t == 0) ? 0 : sc[t - 1];
        if (t == NB - 1) bucketStart[NB] = sc[t];
    }
    __syncthreads();
    sc[t] = (t < NB) ? rowTot[t] : 0;
    __syncthreads();
    for (int off = 1; off < 256; off <<= 1) {
        int v = sc[t];
        int a = (t >= off) ? sc[t - off] : 0;
        __syncthreads();
        sc[t] = v + a;
        __syncthreads();
    }
    if (t < NB) {
        rowStart[t] = (t == 0) ? 0 : sc[t - 1];
        if (t == NB - 1) rowStart[NB] = sc[t];
    }
    if (t == 0) {
        int run = 0;
        for (int i = 0; i < 8; ++i) { labCur[i] = run; run += labCnt[i]; }
    }
}

// K5: partition edges into bucket-contiguous S (packed (row<<8)|(col&255)) and Sr (u8 row&255).
// Bases come from bucketStart + per-chunk prefix; LDS cursors only, zero global atomics.
__global__ void partition_kernel(const int* __restrict__ row, const int* __restrict__ col,
                                 const int* __restrict__ Hc, const int* __restrict__ Hr,
                                 const int* __restrict__ bucketStart, const int* __restrict__ rowStart,
                                 u32* __restrict__ S, u8* __restrict__ Sr) {
    __shared__ int bc_[NB], br_[NB];
    int p = blockIdx.x;
    for (int i = threadIdx.x; i < NB; i += PT) {
        bc_[i] = bucketStart[i] + Hc[p * NB + i];
        br_[i] = rowStart[i]   + Hr[p * NB + i];
    }
    __syncthreads();
    int e0 = p * CHK, e1 = min(e0 + CHK, E_EDGES);
    for (int e = e0 + threadIdx.x; e < e1; e += PT) {
        int r = row[e], c = col[e];
        int pc = atomicAdd(&bc_[c >> 8], 1);
        S[pc] = ((u32)r << 8) | (u32)(c & 255);
        int pr = atomicAdd(&br_[r >> 8], 1);
        Sr[pr] = (u8)(r & 255);
    }
}

// K6: compact nodes grouped by label (block-ranked, 8 global atomics per block)
__global__ void label_fill_kernel(const int* __restrict__ label, int* __restrict__ labCur,
                                  int* __restrict__ nodeByLabel) {
    __shared__ int h[8], base[8], c2[8];
    int t = threadIdx.x;
    if (t < 8) { h[t] = 0; c2[t] = 0; }
    __syncthreads();
    int n = blockIdx.x * 256 + t;
    int l = 0;
    if (n < N_NODES) { l = label[n]; atomicAdd(&h[l], 1); }
    __syncthreads();
    if (t < 8 && h[t] > 0) base[t] = atomicAdd(&labCur[t], h[t]);
    __syncthreads();
    if (n < N_NODES) {
        int pos = base[l] + atomicAdd(&c2[l], 1);
        nodeByLabel[pos] = n;
    }
}

// K7: fused fine-CSR (blocks 0..NB-1) + degree/dinv (blocks NB..2NB-1).
__global__ void csr_deg_kernel(const u32* __restrict__ S, const u8* __restrict__ Sr,
                               const int* __restrict__ bucketStart, const int* __restrict__ rowStart,
                               int* __restrict__ start, u16* __restrict__ srcrow,
                               float* __restrict__ dinv) {
    __shared__ int h[CPB], cur[CPB], sc[CPB];
    int t = threadIdx.x;
    if (blockIdx.x >= NB) {
        // degree branch: LDS histogram of Sr bucket -> dinv
        int b = blockIdx.x - NB;
        if (t < CPB) h[t] = 0;
        __syncthreads();
        int e0 = rowStart[b], e1 = rowStart[b + 1];
        for (int e = e0 + t; e < e1; e += PT) atomicAdd(&h[Sr[e]], 1);
        __syncthreads();
        if (t < CPB) {
            int n = b * CPB + t;
            if (n < N_NODES) dinv[n] = rsqrtf((float)(h[t] + 1));
        }
        return;
    }
    int b = blockIdx.x;
    if (t < CPB) h[t] = 0;
    __syncthreads();
    int e0 = bucketStart[b], e1 = bucketStart[b + 1];
    for (int e = e0 + t; e < e1; e += PT) atomicAdd(&h[S[e] & 255u], 1);
    __syncthreads();
    if (t < CPB) sc[t] = h[t];
    __syncthreads();
    for (int off = 1; off < CPB; off <<= 1) {
        int v = 0, a = 0;
        if (t < CPB) { v = sc[t]; a = (t >= off) ? sc[t - off] : 0; }
        __syncthreads();
        if (t < CPB) sc[t] = v + a;
        __syncthreads();
    }
    if (t < CPB) {
        int base = (t == 0) ? 0 : sc[t - 1];
        int gcol = b * CPB + t;
        if (gcol < N_NODES) start[gcol] = e0 + base;
        cur[t] = base;
    }
    if (b == NB - 1 && t == 0) start[N_NODES] = E_EDGES;
    __syncthreads();
    for (int e = e0 + t; e < e1; e += PT) {
        u32 v = S[e];
        int pos = atomicAdd(&cur[v & 255u], 1);
        srcrow[e0 + pos] = (u16)(v >> 8);
    }
}

// K8: label-grouped node transform -> bf16 messages.
__global__ void node_msg_kernel(const float* __restrict__ x,
                                const int* __restrict__ cnt,
                                const int* __restrict__ label,
                                const float* __restrict__ dinv,
                                const float* __restrict__ W,
                                const float* __restrict__ Wid,
                                const int* __restrict__ nodeByLabel,
                                __hip_bfloat16* __restrict__ msgb) {
    __shared__ float xs[GB][C_DIM];
    __shared__ int nid[GB], lab[GB], cc[GB];
    int t = threadIdx.x;
    if (t < GB) {
        int n = nodeByLabel[blockIdx.x * GB + t];
        nid[t] = n; lab[t] = label[n]; cc[t] = cnt[n];
    }
    __syncthreads();
    #pragma unroll
    for (int g = 0; g < GB; ++g)
        xs[g][t] = __builtin_nontemporal_load(x + (size_t)nid[g] * C_DIM + t);
    __syncthreads();
    for (int g = 0; g < GB; ++g) {          // ego update (~4% of nodes)
        int c = cc[g];
        if (c > 0) {
            float acc = 0.f;
            #pragma unroll 8
            for (int k = 0; k < C_DIM; ++k) acc += xs[g][k] * W[k * C_DIM + t];
            __syncthreads();
            xs[g][t] += (float)c * acc;
            __syncthreads();
        }
    }
    float res[GB];
    #pragma unroll
    for (int g = 0; g < GB; ++g) res[g] = xs[g][t];
    if (lab[0] == lab[GB - 1]) {
        int L = lab[0];
        if (L > 0) {
            const float* Wl = Wid + (size_t)(L - 1) * C_DIM * C_DIM;
            float acc[GB];
            #pragma unroll
            for (int g = 0; g < GB; ++g) acc[g] = 0.f;
            for (int k = 0; k < C_DIM; ++k) {
                float w = Wl[k * C_DIM + t];
                #pragma unroll
                for (int g = 0; g < GB; ++g) acc[g] += xs[g][k] * w;
            }
            #pragma unroll
            for (int g = 0; g < GB; ++g) res[g] += acc[g];
        }
    } else {
        for (int g = 0; g < GB; ++g) {
            int L = lab[g];
            if (L > 0) {
                const float* Wl = Wid + (size_t)(L - 1) * C_DIM * C_DIM;
                float acc = 0.f;
                #pragma unroll 8
                for (int k = 0; k < C_DIM; ++k) acc += xs[g][k] * Wl[k * C_DIM + t];
                res[g] += acc;
            }
        }
    }
    #pragma unroll
    for (int g = 0; g < GB; ++g) {
        int n = nid[g];
        msgb[(size_t)n * C_DIM + t] = __float2bfloat16(dinv[n] * res[g]);
    }
}

// K9: gather + finalize. One wave per dest node; lane owns a bf16 channel pair.
__global__ void gather_kernel(const int* __restrict__ start,
                              const u16* __restrict__ srcrow,
                              const float* __restrict__ dinv,
                              const u32* __restrict__ m32,   // bf16x2-packed msg
                              float* __restrict__ out) {
    int wid  = threadIdx.x >> 6;
    int lane = threadIdx.x & 63;
    int c = blockIdx.x * 4 + wid;
    int e0 = start[c], e1 = start[c + 1];
    u32 u = m32[((u32)c << 6) | lane];                       // self-loop message
    float a0 = __uint_as_float(u << 16);
    float a1 = __uint_as_float(u & 0xffff0000u);
    int e = e0;
    for (; e + 8 <= e1; e += 8) {
        u32 rr[8], uu[8];
        #pragma unroll
        for (int j = 0; j < 8; ++j) rr[j] = srcrow[e + j];
        #pragma unroll
        for (int j = 0; j < 8; ++j) uu[j] = m32[(rr[j] << 6) | (u32)lane];
        #pragma unroll
        for (int j = 0; j < 8; ++j) {
            a0 += __uint_as_float(uu[j] << 16);
            a1 += __uint_as_float(uu[j] & 0xffff0000u);
        }
    }
    for (; e < e1; ++e) {
        u32 ue = m32[((u32)srcrow[e] << 6) | (u32)lane];
        a0 += __uint_as_float(ue << 16);
        a1 += __uint_as_float(ue & 0xffff0000u);
    }
    float di = dinv[c];
    f32x2 o; o.x = di * a0; o.y = di * a1;
    __builtin_nontemporal_store(o, (f32x2*)out + (((u32)c << 6) | lane));
}

extern "C" void kernel_launch(void* const* d_in, const int* in_sizes, int n_in,
                              void* d_out, int out_size, void* d_ws, size_t ws_size,
                              hipStream_t stream) {
    const float* x     = (const float*)d_in[0];
    const int*   edge  = (const int*)d_in[1];   // [2][E]
    const int*   id    = (const int*)d_in[2];
    const int*   label = (const int*)d_in[3];
    const float* W     = (const float*)d_in[4];
    const float* Wid   = (const float*)d_in[5];
    float*       out   = (float*)d_out;

    const int* row = edge;
    const int* col = edge + E_EDGES;

    // ws layout:
    // msgb[N*C] bf16 | S[E] u32 | srcrow[E] u16 | Sr[E] u8 | start[N+1] |
    // bucketStart[NB+1] | rowStart[NB+1] | Hc[NP*NB] | Hr[NP*NB] | colTot[NB] | rowTot[NB] |
    // nodeByLabel[N] | dinv[N] f32 | ZERO{ cnt[N] | labCnt[8] | labCur[8] }
    __hip_bfloat16* msgb = (__hip_bfloat16*)d_ws;
    u32* S           = (u32*)(msgb + (size_t)N_NODES * C_DIM);
    u16* srcrow      = (u16*)(S + E_EDGES);
    u8*  Sr          = (u8*)(srcrow + E_EDGES);
    int* start       = (int*)(Sr + E_EDGES);
    int* bucketStart = start + (N_NODES + 1);
    int* rowStart    = bucketStart + (NB + 1);
    int* Hc          = rowStart + (NB + 1);
    int* Hr          = Hc + NP * NB;
    int* colTot      = Hr + NP * NB;
    int* rowTot      = colTot + NB;
    int* nodeByLabel = rowTot + NB;
    float* dinv      = (float*)(nodeByLabel + N_NODES);
    int* cnt         = (int*)(dinv + N_NODES);
    int* labCnt      = cnt + N_NODES;
    int* labCur      = labCnt + 8;

    hipMemsetAsync(cnt, 0, ((size_t)N_NODES + 16) * sizeof(int), stream);

    label_hist_kernel <<<196, 256, 0, stream>>>(label, labCnt, id, cnt);
    chunk_hist_kernel <<<NP, PT, 0, stream>>>(row, col, Hc, Hr);
    offsets_kernel    <<<2 * NB, PT, 0, stream>>>(Hc, Hr, colTot, rowTot);
    bucket_scan_kernel<<<1, 256, 0, stream>>>(colTot, rowTot, bucketStart, rowStart,
                                              labCnt, labCur);
    partition_kernel  <<<NP, PT, 0, stream>>>(row, col, Hc, Hr, bucketStart, rowStart, S, Sr);
    label_fill_kernel <<<196, 256, 0, stream>>>(label, labCur, nodeByLabel);
    csr_deg_kernel    <<<2 * NB, PT, 0, stream>>>(S, Sr, bucketStart, rowStart,
                                                  start, srcrow, dinv);
    node_msg_kernel   <<<N_NODES / GB, C_DIM, 0, stream>>>(x, cnt, label, dinv, W, Wid,
                                                           nodeByLabel, msgb);
    gather_kernel     <<<N_NODES / 4, 256, 0, stream>>>(start, srcrow, dinv,
                                                        (const u32*)msgb, out);
}